// Round 2
// baseline (745.094 us; speedup 1.0000x reference)
//
#include <hip/hip_runtime.h>

#define BSZ   128
#define CC    2048
#define HW    196
#define NDESC 32
#define NANS  1845
#define ATILES ((NANS + 7) / 8)   // 231

typedef float f4 __attribute__((ext_vector_type(4)));

// ---------------------------------------------------------------------------
// Kernel A: attended[b][c] = (1/196) * sum_hw mask[b][hw] * feat[b][c][hw]
// One wave per (b,c) row; block 0 additionally builds the per-instance
// grouping lists (runs before the gemm kernel in stream order).
// ---------------------------------------------------------------------------
__global__ __launch_bounds__(256) void attend_group_kernel(
        const float* __restrict__ mask,
        const float* __restrict__ feat,
        const int*  __restrict__ inst,
        float* __restrict__ attended,
        int* __restrict__ counts,
        int* __restrict__ lists) {
    int row  = blockIdx.x * 4 + (threadIdx.x >> 6);   // row = b*CC + c
    int lane = threadIdx.x & 63;
    int b    = row >> 11;                             // CC = 2048

    const f4* frow = (const f4*)(feat + (size_t)row * HW);
    const f4* mrow = (const f4*)(mask + (size_t)b * HW);

    float partial = 0.f;
    if (lane < 49) {                                  // 49*4 = 196
        f4 f = frow[lane];
        f4 m = mrow[lane];
        partial = f.x * m.x + f.y * m.y + f.z * m.z + f.w * m.w;
    }
    #pragma unroll
    for (int off = 32; off; off >>= 1)
        partial += __shfl_xor(partial, off, 64);
    if (lane == 0) attended[row] = partial * (1.f / 196.f);

    if (blockIdx.x == 0) {                            // block-uniform branch
        int t = threadIdx.x;
        if (t < NDESC) counts[t] = 0;
        __syncthreads();
        if (t < BSZ) {
            int i = inst[t];
            int slot = atomicAdd(&counts[i], 1);
            lists[i * BSZ + slot] = t;
        }
    }
}

// ---------------------------------------------------------------------------
// Kernel B: grouped GEMM. Grid = NDESC * 231 blocks, 4 waves each; each wave
// holds 2 W rows in registers (non-temporal loads: W is read-once and must
// not evict `attended` from L2). j-loop unrolled 2-deep for ILP across the
// shuffle-reduce chains.
// ---------------------------------------------------------------------------
__global__ __launch_bounds__(256) void gemm_kernel(
        const float* __restrict__ attended,
        const float* __restrict__ W,
        const float* __restrict__ bias,
        const int* __restrict__ counts,
        const int* __restrict__ lists,
        float* __restrict__ out) {
    int ins  = blockIdx.x / ATILES;
    int tile = blockIdx.x % ATILES;
    int cnt  = counts[ins];
    if (cnt == 0) return;                 // unused instance: skip W entirely

    int wid  = threadIdx.x >> 6;
    int lane = threadIdx.x & 63;
    int a0   = tile * 8 + wid * 2;
    int a1   = a0 + 1;
    bool v0  = a0 < NANS;
    bool v1  = a1 < NANS;

    const float* Wb = W + (size_t)ins * NANS * CC;

    f4 w0[8], w1[8];
    if (v0) {
        const f4* wr = (const f4*)(Wb + (size_t)a0 * CC) + lane;
        #pragma unroll
        for (int k = 0; k < 8; ++k) w0[k] = __builtin_nontemporal_load(wr + k * 64);
    }
    if (v1) {
        const f4* wr = (const f4*)(Wb + (size_t)a1 * CC) + lane;
        #pragma unroll
        for (int k = 0; k < 8; ++k) w1[k] = __builtin_nontemporal_load(wr + k * 64);
    }
    float b0 = v0 ? bias[ins * NANS + a0] : 0.f;
    float b1 = v1 ? bias[ins * NANS + a1] : 0.f;

    const int* lst = lists + ins * BSZ;

    for (int j = 0; j < cnt; j += 2) {
        int  bj0 = lst[j];
        bool h1  = (j + 1) < cnt;
        int  bj1 = h1 ? lst[j + 1] : bj0;
        const f4* ar0 = (const f4*)(attended + (size_t)bj0 * CC) + lane;
        const f4* ar1 = (const f4*)(attended + (size_t)bj1 * CC) + lane;

        float acc00 = 0.f, acc01 = 0.f, acc10 = 0.f, acc11 = 0.f;
        #pragma unroll
        for (int k = 0; k < 8; ++k) {
            f4 x = ar0[k * 64];
            f4 y = ar1[k * 64];
            acc00 += x.x * w0[k].x + x.y * w0[k].y + x.z * w0[k].z + x.w * w0[k].w;
            acc01 += x.x * w1[k].x + x.y * w1[k].y + x.z * w1[k].z + x.w * w1[k].w;
            acc10 += y.x * w0[k].x + y.y * w0[k].y + y.z * w0[k].z + y.w * w0[k].w;
            acc11 += y.x * w1[k].x + y.y * w1[k].y + y.z * w1[k].z + y.w * w1[k].w;
        }
        #pragma unroll
        for (int off = 32; off; off >>= 1) {          // two independent pairs
            acc00 += __shfl_xor(acc00, off, 64);
            acc01 += __shfl_xor(acc01, off, 64);
            acc10 += __shfl_xor(acc10, off, 64);
            acc11 += __shfl_xor(acc11, off, 64);
        }
        if (lane == 0) {
            if (v0) out[(size_t)bj0 * NANS + a0] = acc00 + b0;
            if (v1) out[(size_t)bj0 * NANS + a1] = acc01 + b1;
            if (h1) {
                if (v0) out[(size_t)bj1 * NANS + a0] = acc10 + b0;
                if (v1) out[(size_t)bj1 * NANS + a1] = acc11 + b1;
            }
        }
    }
}

// ---------------------------------------------------------------------------
extern "C" void kernel_launch(void* const* d_in, const int* in_sizes, int n_in,
                              void* d_out, int out_size, void* d_ws, size_t ws_size,
                              hipStream_t stream) {
    const float* mask = (const float*)d_in[0];   // [128,1,14,14]
    const float* feat = (const float*)d_in[1];   // [128,2048,14,14]
    const int*   inst = (const int*)d_in[2];     // [128]
    const float* W    = (const float*)d_in[3];   // [32,1845,2048]
    const float* bias = (const float*)d_in[4];   // [32,1845]
    float*       out  = (float*)d_out;           // [128,1845]

    float* attended = (float*)d_ws;                                   // 1 MB
    int*   counts   = (int*)((char*)d_ws + (size_t)BSZ * CC * sizeof(float));
    int*   lists    = counts + NDESC;                                 // 32*128

    attend_group_kernel<<<(BSZ * CC) / 4, 256, 0, stream>>>(
        mask, feat, inst, attended, counts, lists);
    gemm_kernel<<<NDESC * ATILES, 256, 0, stream>>>(
        attended, W, bias, counts, lists, out);
}

// Round 3
// 717.621 us; speedup vs baseline: 1.0383x; 1.0383x over previous
//
#include <hip/hip_runtime.h>

#define BSZ   128
#define CC    2048
#define HW    196
#define NDESC 32
#define NANS  1845

#define TROWS  16                               // A-rows per block
#define ATILES ((NANS + TROWS - 1) / TROWS)     // 116
#define GRID2  (NDESC * ATILES)                 // 3712 (divisible by 8)

typedef float f4 __attribute__((ext_vector_type(4)));

// ---------------------------------------------------------------------------
// Kernel A: attended[b][c] = (1/196) * sum_hw mask[b][hw] * feat[b][c][hw]
// One wave per (b,c) row; block 0 additionally builds the per-instance
// grouping lists (completes before the gemm kernel in stream order).
// ---------------------------------------------------------------------------
__global__ __launch_bounds__(256) void attend_group_kernel(
        const float* __restrict__ mask,
        const float* __restrict__ feat,
        const int*  __restrict__ inst,
        float* __restrict__ attended,
        int* __restrict__ counts,
        int* __restrict__ lists) {
    int row  = blockIdx.x * 4 + (threadIdx.x >> 6);   // row = b*CC + c
    int lane = threadIdx.x & 63;
    int b    = row >> 11;                             // CC = 2048

    const f4* frow = (const f4*)(feat + (size_t)row * HW);
    const f4* mrow = (const f4*)(mask + (size_t)b * HW);

    float partial = 0.f;
    if (lane < 49) {                                  // 49*4 = 196
        f4 f = frow[lane];
        f4 m = mrow[lane];
        partial = f.x * m.x + f.y * m.y + f.z * m.z + f.w * m.w;
    }
    #pragma unroll
    for (int off = 32; off; off >>= 1)
        partial += __shfl_xor(partial, off, 64);
    if (lane == 0) attended[row] = partial * (1.f / 196.f);

    if (blockIdx.x == 0) {                            // block-uniform branch
        int t = threadIdx.x;
        if (t < NDESC) counts[t] = 0;
        __syncthreads();
        if (t < BSZ) {
            int i = inst[t];
            int slot = atomicAdd(&counts[i], 1);
            lists[i * BSZ + slot] = t;
        }
    }
}

// ---------------------------------------------------------------------------
// Kernel B: grouped GEMM. 3712 blocks (XCD-chunked swizzle), 512 threads =
// 8 waves x 2 A-rows. W rows live in registers (read exactly once,
// nontemporal). attended rows are LDS-staged once per member (double-
// buffered, one barrier per member) -> no cache-dependent re-fetch.
// ---------------------------------------------------------------------------
__global__ __launch_bounds__(512) void gemm_kernel(
        const float* __restrict__ attended,
        const float* __restrict__ W,
        const float* __restrict__ bias,
        const int* __restrict__ counts,
        const int* __restrict__ lists,
        float* __restrict__ out) {
    // XCD-chunked mapping: consecutive logical blocks (same instance) share
    // an XCD's L2.  3712 % 8 == 0 so this is bijective.
    int bid     = blockIdx.x;
    int logical = (bid & 7) * (GRID2 / 8) + (bid >> 3);
    int ins     = logical / ATILES;
    int tile    = logical % ATILES;
    int cnt     = counts[ins];
    if (cnt == 0) return;                 // unused instance: skip W entirely

    int tid  = threadIdx.x;
    int wid  = tid >> 6;
    int lane = tid & 63;
    int a0   = tile * TROWS + wid * 2;
    int a1   = a0 + 1;
    bool v0  = a0 < NANS;
    bool v1  = a1 < NANS;

    const float* Wb = W + (size_t)ins * NANS * CC;

    f4 w0[8], w1[8];
    if (v0) {
        const f4* wr = (const f4*)(Wb + (size_t)a0 * CC) + lane;
        #pragma unroll
        for (int k = 0; k < 8; ++k) w0[k] = __builtin_nontemporal_load(wr + k * 64);
    }
    if (v1) {
        const f4* wr = (const f4*)(Wb + (size_t)a1 * CC) + lane;
        #pragma unroll
        for (int k = 0; k < 8; ++k) w1[k] = __builtin_nontemporal_load(wr + k * 64);
    }
    float b0 = v0 ? bias[ins * NANS + a0] : 0.f;
    float b1 = v1 ? bias[ins * NANS + a1] : 0.f;

    __shared__ float lds[2][CC];          // 16 KiB double buffer
    const int* lst = lists + ins * BSZ;

    // prefetch member 0 row into registers (1 f4 per thread covers 2048)
    f4 stage = *((const f4*)(attended + (size_t)lst[0] * CC) + tid);

    for (int j = 0; j < cnt; ++j) {
        int buf = j & 1;
        ((f4*)lds[buf])[tid] = stage;
        if (j + 1 < cnt)
            stage = *((const f4*)(attended + (size_t)lst[j + 1] * CC) + tid);
        __syncthreads();                  // single barrier: see WAR analysis

        float acc0 = 0.f, acc1 = 0.f;
        #pragma unroll
        for (int k = 0; k < 8; ++k) {
            f4 x = ((const f4*)lds[buf])[lane + k * 64];
            acc0 += x.x * w0[k].x + x.y * w0[k].y + x.z * w0[k].z + x.w * w0[k].w;
            acc1 += x.x * w1[k].x + x.y * w1[k].y + x.z * w1[k].z + x.w * w1[k].w;
        }
        #pragma unroll
        for (int off = 32; off; off >>= 1) {
            acc0 += __shfl_xor(acc0, off, 64);
            acc1 += __shfl_xor(acc1, off, 64);
        }
        if (lane == 0) {
            int bj = lst[j];
            if (v0) out[(size_t)bj * NANS + a0] = acc0 + b0;
            if (v1) out[(size_t)bj * NANS + a1] = acc1 + b1;
        }
    }
}

// ---------------------------------------------------------------------------
extern "C" void kernel_launch(void* const* d_in, const int* in_sizes, int n_in,
                              void* d_out, int out_size, void* d_ws, size_t ws_size,
                              hipStream_t stream) {
    const float* mask = (const float*)d_in[0];   // [128,1,14,14]
    const float* feat = (const float*)d_in[1];   // [128,2048,14,14]
    const int*   inst = (const int*)d_in[2];     // [128]
    const float* W    = (const float*)d_in[3];   // [32,1845,2048]
    const float* bias = (const float*)d_in[4];   // [32,1845]
    float*       out  = (float*)d_out;           // [128,1845]

    float* attended = (float*)d_ws;                                   // 1 MB
    int*   counts   = (int*)((char*)d_ws + (size_t)BSZ * CC * sizeof(float));
    int*   lists    = counts + NDESC;                                 // 32*128

    attend_group_kernel<<<(BSZ * CC) / 4, 256, 0, stream>>>(
        mask, feat, inst, attended, counts, lists);
    gemm_kernel<<<GRID2, 512, 0, stream>>>(
        attended, W, bias, counts, lists, out);
}